// Round 2
// baseline (497.013 us; speedup 1.0000x reference)
//
#include <hip/hip_runtime.h>
#include <math.h>

#define NTOK   16384
#define DMODEL 4096
#define NEXP   64
#define KSPLIT 2                 // K-split across blocks (grid doubles -> 2 blocks/CU)
#define WAVES  8                 // waves per block (512 thr: spill-free regalloc)
#define TOKS   64                // tokens per block (lane = token)
#define KPW    (DMODEL / (KSPLIT * WAVES))  // 256 k per wave
#define KT     32                // k per chunk: 128 B contiguous per lane
#define NCHUNK (KPW / KT)        // 8 chunks

#define LD4(p) (*(const float4*)(p))

// one k-step: 64 FMAs, W row via wave-uniform (scalar) loads
#define FMA_K(vv, kk) do {                                   \
    const float* wr = wbase + (size_t)(kk) * NEXP;           \
    _Pragma("unroll")                                        \
    for (int e = 0; e < NEXP; ++e)                           \
        acc[e] = fmaf(wr[e], (vv), acc[e]);                  \
} while (0)

#define DO4(q, kc) do {                                      \
    FMA_K((q).x, (kc) + 0);                                  \
    FMA_K((q).y, (kc) + 1);                                  \
    FMA_K((q).z, (kc) + 2);                                  \
    FMA_K((q).w, (kc) + 3);                                  \
} while (0)

// Kernel A: partial logits for one K-half.  ws layout: [KSPLIT][NEXP][NTOK]
__global__ __launch_bounds__(WAVES * 64, 4)
void router_partial(const float* __restrict__ x,
                    const float* __restrict__ W,
                    float* __restrict__ ws)
{
    // two concurrent 4-round reduction chains (waves 0-3 -> la, 4-7 -> lb)
    __shared__ float la[NEXP * TOKS];
    __shared__ float lb[NEXP * TOKS];

    const int tid  = threadIdx.x;
    const int lane = tid & 63;
    const int wid  = tid >> 6;
    const int t0   = blockIdx.x * TOKS;
    const int kp   = blockIdx.y;                 // which K-half

    // wave-uniform K-slab offset -> W loads become s_load_*
    const int kb = __builtin_amdgcn_readfirstlane((kp * WAVES + wid) * KPW);

    const float* wbase = W + (size_t)kb * NEXP;                    // uniform
    const float* xrow  = x + (size_t)(t0 + lane) * DMODEL + kb;    // per-lane

    float acc[NEXP];
#pragma unroll
    for (int e = 0; e < NEXP; ++e) acc[e] = 0.f;

    // named-register x buffer (NO private arrays / pointer casts -> no scratch)
    float4 c0 = LD4(xrow + 0),  c1 = LD4(xrow + 4),
           c2 = LD4(xrow + 8),  c3 = LD4(xrow + 12),
           c4 = LD4(xrow + 16), c5 = LD4(xrow + 20),
           c6 = LD4(xrow + 24), c7 = LD4(xrow + 28);

    for (int c = 0; c < NCHUNK - 1; ++c) {
        const float* nx = xrow + (c + 1) * KT;
        // prefetch next chunk while computing current
        float4 n0 = LD4(nx + 0),  n1 = LD4(nx + 4),
               n2 = LD4(nx + 8),  n3 = LD4(nx + 12),
               n4 = LD4(nx + 16), n5 = LD4(nx + 20),
               n6 = LD4(nx + 24), n7 = LD4(nx + 28);
        const int kc = c * KT;
        DO4(c0, kc + 0);  DO4(c1, kc + 4);
        DO4(c2, kc + 8);  DO4(c3, kc + 12);
        DO4(c4, kc + 16); DO4(c5, kc + 20);
        DO4(c6, kc + 24); DO4(c7, kc + 28);
        c0 = n0; c1 = n1; c2 = n2; c3 = n3;
        c4 = n4; c5 = n5; c6 = n6; c7 = n7;
    }
    {
        const int kc = (NCHUNK - 1) * KT;
        DO4(c0, kc + 0);  DO4(c1, kc + 4);
        DO4(c2, kc + 8);  DO4(c3, kc + 12);
        DO4(c4, kc + 16); DO4(c5, kc + 20);
        DO4(c6, kc + 24); DO4(c7, kc + 28);
    }

    // cross-wave reduction: two concurrent serial chains of 4 waves each
    {
        float* dst = (wid < 4) ? la : lb;
        const int slot = wid & 3;
        for (int r = 0; r < 4; ++r) {
            if (slot == r) {
                if (r == 0) {
#pragma unroll
                    for (int e = 0; e < NEXP; ++e) dst[e * TOKS + lane] = acc[e];
                } else {
#pragma unroll
                    for (int e = 0; e < NEXP; ++e) dst[e * TOKS + lane] += acc[e];
                }
            }
            __syncthreads();
        }
    }

    // store partial logits, all 8 waves, coalesced: ws[kp][e][t]
    {
        const int e0 = wid * 8;
#pragma unroll
        for (int i = 0; i < 8; ++i) {
            const int e = e0 + i;
            ws[((size_t)kp * NEXP + e) * NTOK + t0 + lane] =
                la[e * TOKS + lane] + lb[e * TOKS + lane];
        }
    }
}

// Kernel B: combine K-halves, bias, softmax, top-2.  One token per thread.
__global__ __launch_bounds__(64)
void router_finalize(const float* __restrict__ ws,
                     const float* __restrict__ b,
                     float* __restrict__ out)
{
    const int t = blockIdx.x * 64 + threadIdx.x;

    float l[NEXP];
    float m = -INFINITY;
#pragma unroll
    for (int e = 0; e < NEXP; ++e) {
        l[e] = ws[(size_t)e * NTOK + t]
             + ws[((size_t)NEXP + e) * NTOK + t]
             + b[e];
        m = fmaxf(m, l[e]);
    }
    float Z = 0.f;
#pragma unroll
    for (int e = 0; e < NEXP; ++e) {
        l[e] = expf(l[e] - m);
        Z += l[e];
    }
    // top-2 over probs, ties -> lower index (jax.lax.top_k semantics)
    float p1 = -1.f, p2 = -1.f;
    int i1 = 0, i2 = 0;
#pragma unroll
    for (int e = 0; e < NEXP; ++e) {
        const float p = l[e] / Z;
        if (p > p1) { p2 = p1; i2 = i1; p1 = p; i1 = e; }
        else if (p > p2) { p2 = p; i2 = e; }
    }
    const float s = p1 + p2;
    out[2 * t]     = p1 / s;
    out[2 * t + 1] = p2 / s;
    // indices written as float: harness reads the whole output as f32
    out[2 * NTOK + 2 * t]     = (float)i1;
    out[2 * NTOK + 2 * t + 1] = (float)i2;
}

extern "C" void kernel_launch(void* const* d_in, const int* in_sizes, int n_in,
                              void* d_out, int out_size, void* d_ws, size_t ws_size,
                              hipStream_t stream) {
    const float* x = (const float*)d_in[0];
    const float* W = (const float*)d_in[1];
    const float* b = (const float*)d_in[2];
    float* out = (float*)d_out;
    float* ws  = (float*)d_ws;   // needs KSPLIT*NEXP*NTOK*4 = 8 MB

    router_partial<<<dim3(NTOK / TOKS, KSPLIT), dim3(WAVES * 64), 0, stream>>>(x, W, ws);
    router_finalize<<<dim3(NTOK / 64), dim3(64), 0, stream>>>(ws, b, out);
}

// Round 3
// 466.930 us; speedup vs baseline: 1.0644x; 1.0644x over previous
//
#include <hip/hip_runtime.h>
#include <math.h>

#define NTOK   16384
#define DMODEL 4096
#define NEXP   64
#define KSPLIT 2                 // K-split across blocks -> grid 512 = 2 blocks/CU
#define WAVES  8                 // waves per block
#define TOKS   64                // tokens per block (lane = token)
#define KPW    (DMODEL / (KSPLIT * WAVES))  // 256 k per wave
#define KT     16                // k per chunk: 64 B contiguous per lane (was 32)
#define NCHUNK (KPW / KT)        // 16 chunks

#define LD4(p) (*(const float4*)(p))

// one k-step: 64 FMAs, W row via wave-uniform (scalar) loads
#define FMA_K(vv, kk) do {                                   \
    const float* wr = wbase + (size_t)(kk) * NEXP;           \
    _Pragma("unroll")                                        \
    for (int e = 0; e < NEXP; ++e)                           \
        acc[e] = fmaf(wr[e], (vv), acc[e]);                  \
} while (0)

#define DO4(q, kc) do {                                      \
    FMA_K((q).x, (kc) + 0);                                  \
    FMA_K((q).y, (kc) + 1);                                  \
    FMA_K((q).z, (kc) + 2);                                  \
    FMA_K((q).w, (kc) + 3);                                  \
} while (0)

// Kernel A: partial logits for one K-half.  ws layout: [KSPLIT][NEXP][NTOK]
__global__ __launch_bounds__(WAVES * 64, 4)
void router_partial(const float* __restrict__ x,
                    const float* __restrict__ W,
                    float* __restrict__ ws)
{
    // two concurrent 4-round reduction chains (waves 0-3 -> la, 4-7 -> lb)
    __shared__ float la[NEXP * TOKS];
    __shared__ float lb[NEXP * TOKS];

    const int tid  = threadIdx.x;
    const int lane = tid & 63;
    const int wid  = tid >> 6;
    const int t0   = blockIdx.x * TOKS;
    const int kp   = blockIdx.y;                 // which K-half

    // wave-uniform K-slab offset -> W loads become s_load_*
    const int kb = __builtin_amdgcn_readfirstlane((kp * WAVES + wid) * KPW);

    const float* wbase = W + (size_t)kb * NEXP;                    // uniform
    const float* xrow  = x + (size_t)(t0 + lane) * DMODEL + kb;    // per-lane

    float acc[NEXP];
#pragma unroll
    for (int e = 0; e < NEXP; ++e) acc[e] = 0.f;

    // x double-buffer: 4 float4 current + 4 float4 next = 32 VGPRs total,
    // keeping arch-VGPR need under the 64 left beside the 64-AGPR acc.
    float4 c0 = LD4(xrow + 0),  c1 = LD4(xrow + 4),
           c2 = LD4(xrow + 8),  c3 = LD4(xrow + 12);

    for (int c = 0; c < NCHUNK - 1; ++c) {
        const float* nx = xrow + (c + 1) * KT;
        // prefetch next chunk while computing current
        float4 n0 = LD4(nx + 0),  n1 = LD4(nx + 4),
               n2 = LD4(nx + 8),  n3 = LD4(nx + 12);
        const int kc = c * KT;
        DO4(c0, kc + 0);  DO4(c1, kc + 4);
        DO4(c2, kc + 8);  DO4(c3, kc + 12);
        c0 = n0; c1 = n1; c2 = n2; c3 = n3;
    }
    {
        const int kc = (NCHUNK - 1) * KT;
        DO4(c0, kc + 0);  DO4(c1, kc + 4);
        DO4(c2, kc + 8);  DO4(c3, kc + 12);
    }

    // cross-wave reduction: two concurrent serial chains of 4 waves each
    {
        float* dst = (wid < 4) ? la : lb;
        const int slot = wid & 3;
        for (int r = 0; r < 4; ++r) {
            if (slot == r) {
                if (r == 0) {
#pragma unroll
                    for (int e = 0; e < NEXP; ++e) dst[e * TOKS + lane] = acc[e];
                } else {
#pragma unroll
                    for (int e = 0; e < NEXP; ++e) dst[e * TOKS + lane] += acc[e];
                }
            }
            __syncthreads();
        }
    }

    // store partial logits, all 8 waves, coalesced: ws[kp][e][t]
    {
        const int e0 = wid * 8;
#pragma unroll
        for (int i = 0; i < 8; ++i) {
            const int e = e0 + i;
            ws[((size_t)kp * NEXP + e) * NTOK + t0 + lane] =
                la[e * TOKS + lane] + lb[e * TOKS + lane];
        }
    }
}

// Kernel B: combine K-halves, bias, softmax, top-2.  One token per thread.
__global__ __launch_bounds__(64)
void router_finalize(const float* __restrict__ ws,
                     const float* __restrict__ b,
                     float* __restrict__ out)
{
    const int t = blockIdx.x * 64 + threadIdx.x;

    float l[NEXP];
    float m = -INFINITY;
#pragma unroll
    for (int e = 0; e < NEXP; ++e) {
        l[e] = ws[(size_t)e * NTOK + t]
             + ws[((size_t)NEXP + e) * NTOK + t]
             + b[e];
        m = fmaxf(m, l[e]);
    }
    float Z = 0.f;
#pragma unroll
    for (int e = 0; e < NEXP; ++e) {
        l[e] = expf(l[e] - m);
        Z += l[e];
    }
    // top-2 over probs, ties -> lower index (jax.lax.top_k semantics)
    float p1 = -1.f, p2 = -1.f;
    int i1 = 0, i2 = 0;
#pragma unroll
    for (int e = 0; e < NEXP; ++e) {
        const float p = l[e] / Z;
        if (p > p1) { p2 = p1; i2 = i1; p1 = p; i1 = e; }
        else if (p > p2) { p2 = p; i2 = e; }
    }
    const float s = p1 + p2;
    out[2 * t]     = p1 / s;
    out[2 * t + 1] = p2 / s;
    // indices written as float: harness reads the whole output as f32
    out[2 * NTOK + 2 * t]     = (float)i1;
    out[2 * NTOK + 2 * t + 1] = (float)i2;
}

extern "C" void kernel_launch(void* const* d_in, const int* in_sizes, int n_in,
                              void* d_out, int out_size, void* d_ws, size_t ws_size,
                              hipStream_t stream) {
    const float* x = (const float*)d_in[0];
    const float* W = (const float*)d_in[1];
    const float* b = (const float*)d_in[2];
    float* out = (float*)d_out;
    float* ws  = (float*)d_ws;   // needs KSPLIT*NEXP*NTOK*4 = 8 MB

    router_partial<<<dim3(NTOK / TOKS, KSPLIT), dim3(WAVES * 64), 0, stream>>>(x, W, ws);
    router_finalize<<<dim3(NTOK / 64), dim3(64), 0, stream>>>(ws, b, out);
}